// Round 6
// baseline (275.794 us; speedup 1.0000x reference)
//
#include <hip/hip_runtime.h>

// DirectNormLoss: B=16384 rows, D=2048 features, 1000 classes.
// loss = mean_i [ 1 - <s_i, c_i> / (||c_i|| * max(||s_i||, ||t_i||)) ]
//
// R5: t_emb only contributes its row norm -> split work into two phases
// within one kernel: blocks [0,4096) do s.c rows (s NT + c cached, 2
// streams), blocks [4096,6144) do pure t-norm streaming (2 contiguous rows
// per wave, NT, copy-kernel-like). Reduce combines dot/ssq/tsq arrays.
// R4 established NT loads for streamed data are a win (~20%).

#define NROWS  16384
#define DDIM   2048
#define BLK    256
#define WPB    (BLK / 64)                 // 4 waves/block
#define SC_BLOCKS (NROWS / WPB)           // 4096: one s.c row per wave
#define T_BLOCKS  (NROWS / 2 / WPB)       // 2048: two t rows per wave
#define GRID   (SC_BLOCKS + T_BLOCKS)     // 6144

typedef float v4f __attribute__((ext_vector_type(4)));

// ws layout: dot[NROWS] | ssq[NROWS] | tsq[NROWS]
#define WS_DOT 0
#define WS_SSQ NROWS
#define WS_TSQ (2 * NROWS)
#define WS_NEEDED ((size_t)(3 * NROWS) * sizeof(float))

__global__ __launch_bounds__(BLK, 2) void dnl_main_kernel(
    const float* __restrict__ s_emb,
    const float* __restrict__ t_emb,
    const float* __restrict__ T_EMB,
    const int*   __restrict__ labels,
    float*       __restrict__ ws)
{
    const int tid  = threadIdx.x;
    const int lane = tid & 63;
    const int wib  = tid >> 6;            // wave in block

    float* dot = ws + WS_DOT;
    float* ssq = ws + WS_SSQ;
    float* tsq = ws + WS_TSQ;

    if (blockIdx.x < SC_BLOCKS) {
        // ---- phase A: s.c waves, one row per wave ----
        const int row   = blockIdx.x * WPB + wib;
        const int label = labels[row];

        const v4f* s4 = (const v4f*)(s_emb + (size_t)row   * DDIM);
        const v4f* c4 = (const v4f*)(T_EMB + (size_t)label * DDIM);

        float ss = 0.f, sc = 0.f, cc = 0.f;
        #pragma unroll
        for (int j = 0; j < 8; ++j) {
            const int k = lane + j * 64;
            const v4f s = __builtin_nontemporal_load(&s4[k]);
            const v4f c = c4[k];
            ss += s.x*s.x + s.y*s.y + s.z*s.z + s.w*s.w;
            sc += s.x*c.x + s.y*c.y + s.z*c.z + s.w*c.w;
            cc += c.x*c.x + c.y*c.y + c.z*c.z + c.w*c.w;
        }
        #pragma unroll
        for (int off = 32; off > 0; off >>= 1) {
            ss += __shfl_xor(ss, off, 64);
            sc += __shfl_xor(sc, off, 64);
            cc += __shfl_xor(cc, off, 64);
        }
        if (lane == 0) {
            dot[row] = sc / sqrtf(cc);
            ssq[row] = ss;
        }
    } else {
        // ---- phase B: pure t-norm streaming, two contiguous rows/wave ----
        const int i    = (blockIdx.x - SC_BLOCKS) * WPB + wib;
        const int row0 = 2 * i;
        const v4f* t4 = (const v4f*)(t_emb + (size_t)row0 * DDIM);

        float t0 = 0.f, t1 = 0.f;
        #pragma unroll
        for (int j = 0; j < 8; ++j) {
            const v4f a = __builtin_nontemporal_load(&t4[lane + j * 64]);
            const v4f b = __builtin_nontemporal_load(&t4[512 + lane + j * 64]);
            t0 += a.x*a.x + a.y*a.y + a.z*a.z + a.w*a.w;
            t1 += b.x*b.x + b.y*b.y + b.z*b.z + b.w*b.w;
        }
        #pragma unroll
        for (int off = 32; off > 0; off >>= 1) {
            t0 += __shfl_xor(t0, off, 64);
            t1 += __shfl_xor(t1, off, 64);
        }
        if (lane == 0) {
            tsq[row0]     = t0;
            tsq[row0 + 1] = t1;
        }
    }
}

__global__ __launch_bounds__(BLK) void dnl_reduce_kernel(
    const float* __restrict__ ws,
    float*       __restrict__ out)
{
    const int tid = threadIdx.x;
    const float* dot = ws + WS_DOT;
    const float* ssq = ws + WS_SSQ;
    const float* tsq = ws + WS_TSQ;

    float sum = 0.f;
    // 16384 rows / 256 threads = 64 per thread, coalesced stride-256.
    #pragma unroll 4
    for (int i = tid; i < NROWS; i += BLK) {
        const float mn = fmaxf(sqrtf(ssq[i]), sqrtf(tsq[i]));
        sum += 1.0f - dot[i] / mn;
    }

    #pragma unroll
    for (int off = 32; off > 0; off >>= 1)
        sum += __shfl_xor(sum, off, 64);

    __shared__ float red[4];
    if ((tid & 63) == 0) red[tid >> 6] = sum;
    __syncthreads();
    if (tid == 0)
        out[0] = (red[0] + red[1] + red[2] + red[3]) * (1.0f / (float)NROWS);
}

// Atomic fallback (only if ws too small): R4 single-kernel path.
__global__ __launch_bounds__(BLK, 2) void dnl_main_atomic_kernel(
    const float* __restrict__ s_emb,
    const float* __restrict__ t_emb,
    const float* __restrict__ T_EMB,
    const int*   __restrict__ labels,
    float*       __restrict__ out)
{
    const int tid  = threadIdx.x;
    const int lane = tid & 63;
    const int row  = blockIdx.x * WPB + (tid >> 6);
    const int label = labels[row];

    const v4f* s4 = (const v4f*)(s_emb + (size_t)row   * DDIM);
    const v4f* t4 = (const v4f*)(t_emb + (size_t)row   * DDIM);
    const v4f* c4 = (const v4f*)(T_EMB + (size_t)label * DDIM);

    float ss = 0.f, tt = 0.f, sc = 0.f, cc = 0.f;
    #pragma unroll
    for (int j = 0; j < 8; ++j) {
        const int k = lane + j * 64;
        const v4f s = __builtin_nontemporal_load(&s4[k]);
        const v4f t = __builtin_nontemporal_load(&t4[k]);
        const v4f c = c4[k];
        ss += s.x*s.x + s.y*s.y + s.z*s.z + s.w*s.w;
        tt += t.x*t.x + t.y*t.y + t.z*t.z + t.w*t.w;
        sc += s.x*c.x + s.y*c.y + s.z*c.z + s.w*c.w;
        cc += c.x*c.x + c.y*c.y + c.z*c.z + c.w*c.w;
    }
    #pragma unroll
    for (int off = 32; off > 0; off >>= 1) {
        ss += __shfl_xor(ss, off, 64);
        tt += __shfl_xor(tt, off, 64);
        sc += __shfl_xor(sc, off, 64);
        cc += __shfl_xor(cc, off, 64);
    }
    if (lane == 0) {
        const float max_norm = fmaxf(sqrtf(ss), sqrtf(tt));
        atomicAdd(out, (1.0f - sc / (sqrtf(cc) * max_norm)) * (1.0f / (float)NROWS));
    }
}

extern "C" void kernel_launch(void* const* d_in, const int* in_sizes, int n_in,
                              void* d_out, int out_size, void* d_ws, size_t ws_size,
                              hipStream_t stream) {
    const float* s_emb  = (const float*)d_in[0];
    const float* t_emb  = (const float*)d_in[1];
    const float* T_EMB  = (const float*)d_in[2];
    const int*   labels = (const int*)d_in[3];
    float* out = (float*)d_out;

    if (ws_size >= WS_NEEDED) {
        float* ws = (float*)d_ws;
        dnl_main_kernel<<<GRID, BLK, 0, stream>>>(s_emb, t_emb, T_EMB, labels, ws);
        dnl_reduce_kernel<<<1, BLK, 0, stream>>>(ws, out);
    } else {
        hipMemsetAsync(d_out, 0, sizeof(float), stream);
        dnl_main_atomic_kernel<<<NROWS / WPB, BLK, 0, stream>>>(
            s_emb, t_emb, T_EMB, labels, out);
    }
}